// Round 8
// baseline (7391.479 us; speedup 1.0000x reference)
//
#include <hip/hip_runtime.h>
#include <math.h>

// ---------------------------------------------------------------------------
// R8: fix R7's VGPR cliff. R7's CO=64 spilled (VGPR_Count=68 < 64 live accs)
// and hit a grid floor (676 blocks = 2.6/CU). R8: 200^2-class convs use
// CO=32 (grid 1352 = 5.3/CU, ~60 VGPR, no spill) with __launch_bounds__(256,4)
// so the heuristic can't cap below need; 100^2-and-below revert to R6's CO=16.
// Stem CO 4->16 (staging /4). All per-output accumulation chains unchanged ->
// selection bit-identical to R6/R7 (passed, absmax 0.015625).
// ---------------------------------------------------------------------------

#define DI __device__ __forceinline__

typedef short short8 __attribute__((ext_vector_type(8)));
typedef float float16v __attribute__((ext_vector_type(16)));

DI float neg_inf() { return __int_as_float(0xff800000); }

DI unsigned fkey(float f) {
  unsigned u = __float_as_uint(f);
  return (u & 0x80000000u) ? ~u : (u | 0x80000000u);
}

DI unsigned short f2bf(float f) {  // fp32 -> bf16 RN-even
  unsigned u = __float_as_uint(f);
  unsigned r = (u + 0x7FFFu + ((u >> 16) & 1u)) >> 16;
  return (unsigned short)r;
}

// ---------------------------------------------------------------------------
// Stem: fused normalize + 7x7 stride-2 conv + relu. 3x800x800 -> 64x400x400.
// CO=16 (was 4): tin staged 4x less; per-output (c,ky,kx) chain unchanged.
// ---------------------------------------------------------------------------
__global__ __launch_bounds__(256) void stem_conv(const float* __restrict__ x,
                                                 const float* __restrict__ w,
                                                 float* __restrict__ out) {
  __shared__ float tin[3 * 37 * 37];
  __shared__ float tw[16 * 147];
  const int x0 = blockIdx.x * 16, y0 = blockIdx.y * 16, co0 = blockIdx.z * 16;
  const int tid = threadIdx.x;
  for (int i = tid; i < 16 * 147; i += 256) tw[i] = w[co0 * 147 + i];
  const int ix0 = x0 * 2 - 2, iy0 = y0 * 2 - 2;
  const float mean[3] = {0.485f, 0.456f, 0.406f};
  const float stdv[3] = {0.229f, 0.224f, 0.225f};
  for (int i = tid; i < 3 * 37 * 37; i += 256) {
    int c = i / 1369, r = i % 1369, yy = r / 37, xx = r % 37;
    int gy = iy0 + yy, gx = ix0 + xx;
    float v = 0.f;
    if ((unsigned)gy < 800u && (unsigned)gx < 800u)
      v = __fdiv_rn(__fsub_rn(x[c * 640000 + gy * 800 + gx], mean[c]), stdv[c]);
    tin[i] = v;
  }
  __syncthreads();
  const int tx = tid & 15, ty = tid >> 4;
  float acc[16];
#pragma unroll
  for (int co = 0; co < 16; ++co) acc[co] = 0.f;
  for (int c = 0; c < 3; ++c)
    for (int ky = 0; ky < 7; ++ky)
#pragma unroll
      for (int kx = 0; kx < 7; ++kx) {
        float v = tin[c * 1369 + (ty * 2 + ky) * 37 + (tx * 2 + kx)];
        const int wo = c * 49 + ky * 7 + kx;
#pragma unroll
        for (int co = 0; co < 16; ++co)
          acc[co] = fmaf(v, tw[co * 147 + wo], acc[co]);
      }
  int ox = x0 + tx, oy = y0 + ty;
#pragma unroll
  for (int co = 0; co < 16; ++co)
    out[(size_t)(co0 + co) * 160000 + oy * 400 + ox] = fmaxf(acc[co], 0.f);
}

// ---------------------------------------------------------------------------
// Stride-1 3x3 conv: 16x16 px tile, CO couts/block, 1 px/thread.
// tin pitch 24 -> compute-read banks exactly 2-way (free).
// __launch_bounds__(256,4): VGPR ceiling 128 (CO=32 needs ~60; no heuristic
// cap/spill as seen in R7's CO=64 @ 68 VGPR).
// Accumulation order: cb asc, ci asc, ky, kx — identical for any CO.
// ---------------------------------------------------------------------------
template <int CHUNK, int CO, bool RELU>
__global__ __launch_bounds__(256, 4) void conv16_s1(
    const float* __restrict__ in, const float* __restrict__ w,
    float* __restrict__ out, int Cin, int Hin, int Win, int Hout, int Wout) {
  constexpr int P = 24;  // pitch (18 cols used)
  __shared__ __align__(16) float tin[CHUNK * 18 * P];
  __shared__ __align__(16) float tw[CHUNK * 9 * CO];
  const int tid = threadIdx.x;
  const int tx = tid & 15, ty = tid >> 4;
  const int x0 = blockIdx.x * 16, y0 = blockIdx.y * 16;
  const int co0 = blockIdx.z * CO;
  const int ix0 = x0 - 1, iy0 = y0 - 1;
  const size_t HWin = (size_t)Hin * Win;
  float acc[CO];
#pragma unroll
  for (int co = 0; co < CO; ++co) acc[co] = 0.f;

  for (int cb = 0; cb < Cin; cb += CHUNK) {
    for (int i = tid; i < CHUNK * 18 * 18; i += 256) {
      int c = i / 324, r = i % 324;
      int yy = r / 18, xx = r % 18;
      int gy = iy0 + yy, gx = ix0 + xx;
      float v = 0.f;
      if ((unsigned)gy < (unsigned)Hin && (unsigned)gx < (unsigned)Win)
        v = in[(cb + c) * HWin + (size_t)gy * Win + gx];
      tin[c * 18 * P + yy * P + xx] = v;
    }
    for (int i = tid; i < CHUNK * 9 * CO; i += 256) {
      int co = i & (CO - 1), rest = i / CO;
      int ci = rest / 9, kk = rest % 9;
      tw[i] = w[((size_t)(co0 + co) * Cin + cb + ci) * 9 + kk];
    }
    __syncthreads();
    for (int ci = 0; ci < CHUNK; ++ci) {
#pragma unroll
      for (int ky = 0; ky < 3; ++ky) {
#pragma unroll
        for (int kx = 0; kx < 3; ++kx) {
          float v = tin[ci * 18 * P + (ty + ky) * P + tx + kx];
          const float* wp = &tw[(ci * 9 + ky * 3 + kx) * CO];
#pragma unroll
          for (int c4 = 0; c4 < CO / 4; ++c4) {
            float4 wv = *(const float4*)(wp + c4 * 4);
            acc[c4 * 4 + 0] = fmaf(v, wv.x, acc[c4 * 4 + 0]);
            acc[c4 * 4 + 1] = fmaf(v, wv.y, acc[c4 * 4 + 1]);
            acc[c4 * 4 + 2] = fmaf(v, wv.z, acc[c4 * 4 + 2]);
            acc[c4 * 4 + 3] = fmaf(v, wv.w, acc[c4 * 4 + 3]);
          }
        }
      }
    }
    __syncthreads();
  }
  int oy = y0 + ty, ox = x0 + tx;
  if (oy < Hout && ox < Wout) {
#pragma unroll
    for (int co = 0; co < CO; ++co) {
      float v = acc[co];
      if (RELU) v = fmaxf(v, 0.f);
      out[(size_t)(co0 + co) * Hout * Wout + (size_t)oy * Wout + ox] = v;
    }
  }
}

// ---------------------------------------------------------------------------
// Stride-2 3x3 conv: 16x16 px out tile, CO couts/block, 1 px/thread.
// Input span 33x33 phase-split by column parity, pitch 20 -> 2-way (free).
// kx=0 -> E[tx], kx=1 -> O[tx], kx=2 -> E[tx+1]; row = 2ty+ky.
// ---------------------------------------------------------------------------
template <int CHUNK, int CO, bool RELU>
__global__ __launch_bounds__(256, 4) void conv16_s2(
    const float* __restrict__ in, const float* __restrict__ w,
    float* __restrict__ out, int Cin, int Hin, int Win, int Hout, int Wout) {
  constexpr int P = 20;
  __shared__ __align__(16) float tinE[CHUNK * 33 * P];
  __shared__ __align__(16) float tinO[CHUNK * 33 * P];
  __shared__ __align__(16) float tw[CHUNK * 9 * CO];
  const int tid = threadIdx.x;
  const int tx = tid & 15, ty = tid >> 4;
  const int x0 = blockIdx.x * 16, y0 = blockIdx.y * 16;
  const int co0 = blockIdx.z * CO;
  const int ix0 = x0 * 2, iy0 = y0 * 2;
  const size_t HWin = (size_t)Hin * Win;
  float acc[CO];
#pragma unroll
  for (int co = 0; co < CO; ++co) acc[co] = 0.f;

  for (int cb = 0; cb < Cin; cb += CHUNK) {
    for (int i = tid; i < CHUNK * 33 * 33; i += 256) {
      int c = i / 1089, r = i % 1089;
      int yy = r / 33, xx = r % 33;
      int gy = iy0 + yy, gx = ix0 + xx;
      float v = 0.f;
      if ((unsigned)gy < (unsigned)Hin && (unsigned)gx < (unsigned)Win)
        v = in[(cb + c) * HWin + (size_t)gy * Win + gx];
      int idx = c * 33 * P + yy * P + (xx >> 1);
      if (xx & 1) tinO[idx] = v; else tinE[idx] = v;
    }
    for (int i = tid; i < CHUNK * 9 * CO; i += 256) {
      int co = i & (CO - 1), rest = i / CO;
      int ci = rest / 9, kk = rest % 9;
      tw[i] = w[((size_t)(co0 + co) * Cin + cb + ci) * 9 + kk];
    }
    __syncthreads();
    for (int ci = 0; ci < CHUNK; ++ci) {
#pragma unroll
      for (int ky = 0; ky < 3; ++ky) {
#pragma unroll
        for (int kx = 0; kx < 3; ++kx) {
          const float* base = (kx == 1) ? tinO : tinE;
          const int cadd = (kx == 2) ? 1 : 0;
          float v = base[ci * 33 * P + (2 * ty + ky) * P + tx + cadd];
          const float* wp = &tw[(ci * 9 + ky * 3 + kx) * CO];
#pragma unroll
          for (int c4 = 0; c4 < CO / 4; ++c4) {
            float4 wv = *(const float4*)(wp + c4 * 4);
            acc[c4 * 4 + 0] = fmaf(v, wv.x, acc[c4 * 4 + 0]);
            acc[c4 * 4 + 1] = fmaf(v, wv.y, acc[c4 * 4 + 1]);
            acc[c4 * 4 + 2] = fmaf(v, wv.z, acc[c4 * 4 + 2]);
            acc[c4 * 4 + 3] = fmaf(v, wv.w, acc[c4 * 4 + 3]);
          }
        }
      }
    }
    __syncthreads();
  }
  int oy = y0 + ty, ox = x0 + tx;
  if (oy < Hout && ox < Wout) {
#pragma unroll
    for (int co = 0; co < CO; ++co) {
      float v = acc[co];
      if (RELU) v = fmaxf(v, 0.f);
      out[(size_t)(co0 + co) * Hout * Wout + (size_t)oy * Wout + ox] = v;
    }
  }
}

// ---------------------------------------------------------------------------
// RPN head (1x1 cls + 1x1 box) fused with anchor decode. (unchanged R2)
// ---------------------------------------------------------------------------
__global__ __launch_bounds__(256) void rpn_head_decode(
    const float* __restrict__ t, const float* __restrict__ wcls,
    const float* __restrict__ wbox, float* __restrict__ boxes,
    float* __restrict__ scores, int fh, int fw, float stride, float ws0,
    float ws1, float ws2, float hs0, float hs1, float hs2) {
  __shared__ __align__(16) float wcs[256][16];
  for (int i = threadIdx.x; i < 256 * 16; i += 256) {
    int c = i & 255, o = i >> 8;
    float v = 0.f;
    if (o < 3) v = wcls[o * 256 + c];
    else if (o < 15) v = wbox[(o - 3) * 256 + c];
    wcs[c][o] = v;
  }
  __syncthreads();
  const int npix = fh * fw;
  int p = blockIdx.x * 256 + threadIdx.x;
  if (p >= npix) return;
  float a[15];
#pragma unroll
  for (int o = 0; o < 15; ++o) a[o] = 0.f;
#pragma unroll 4
  for (int c = 0; c < 256; ++c) {
    float v = t[(size_t)c * npix + p];
    const float4* wr = (const float4*)&wcs[c][0];
    float4 w0 = wr[0], w1 = wr[1], w2 = wr[2], w3 = wr[3];
    a[0] = fmaf(v, w0.x, a[0]);   a[1] = fmaf(v, w0.y, a[1]);
    a[2] = fmaf(v, w0.z, a[2]);   a[3] = fmaf(v, w0.w, a[3]);
    a[4] = fmaf(v, w1.x, a[4]);   a[5] = fmaf(v, w1.y, a[5]);
    a[6] = fmaf(v, w1.z, a[6]);   a[7] = fmaf(v, w1.w, a[7]);
    a[8] = fmaf(v, w2.x, a[8]);   a[9] = fmaf(v, w2.y, a[9]);
    a[10] = fmaf(v, w2.z, a[10]); a[11] = fmaf(v, w2.w, a[11]);
    a[12] = fmaf(v, w3.x, a[12]); a[13] = fmaf(v, w3.y, a[13]);
    a[14] = fmaf(v, w3.z, a[14]);
  }
  const int i = p / fw, j = p % fw;
  const float acy0 = __fmul_rn((float)i + 0.5f, stride);
  const float acx0 = __fmul_rn((float)j + 0.5f, stride);
  const float WS[3] = {ws0, ws1, ws2}, HS[3] = {hs0, hs1, hs2};
#pragma unroll
  for (int an = 0; an < 3; ++an) {
    float hw = __fmul_rn(WS[an], 0.5f), hh = __fmul_rn(HS[an], 0.5f);
    float x1a = __fsub_rn(acx0, hw), x2a = __fadd_rn(acx0, hw);
    float y1a = __fsub_rn(acy0, hh), y2a = __fadd_rn(acy0, hh);
    float aw = __fsub_rn(x2a, x1a), ah = __fsub_rn(y2a, y1a);
    float acx = __fadd_rn(x1a, __fmul_rn(aw, 0.5f));
    float acy = __fadd_rn(y1a, __fmul_rn(ah, 0.5f));
    float dx = a[3 + an * 4 + 0], dy = a[3 + an * 4 + 1];
    float dw = fminf(fmaxf(a[3 + an * 4 + 2], -4.f), 4.f);
    float dh = fminf(fmaxf(a[3 + an * 4 + 3], -4.f), 4.f);
    float cx = __fadd_rn(acx, __fmul_rn(dx, aw));
    float cy = __fadd_rn(acy, __fmul_rn(dy, ah));
    float w_ = __fmul_rn(aw, expf(dw));
    float h_ = __fmul_rn(ah, expf(dh));
    int idx = p * 3 + an;
    boxes[idx * 4 + 0] =
        fminf(fmaxf(__fsub_rn(cx, __fmul_rn(w_, 0.5f)), 0.f), 800.f);
    boxes[idx * 4 + 1] =
        fminf(fmaxf(__fsub_rn(cy, __fmul_rn(h_, 0.5f)), 0.f), 800.f);
    boxes[idx * 4 + 2] =
        fminf(fmaxf(__fadd_rn(cx, __fmul_rn(w_, 0.5f)), 0.f), 800.f);
    boxes[idx * 4 + 3] =
        fminf(fmaxf(__fadd_rn(cy, __fmul_rn(h_, 0.5f)), 0.f), 800.f);
    scores[idx] = a[an];
  }
}

// ---------------------------------------------------------------------------
// Exact top-k (k=1000) per level: two-pass 16-bit radix select. (unchanged)
// ---------------------------------------------------------------------------
__global__ void hist_hi_kernel(const float* __restrict__ s, int n,
                               int* __restrict__ hist) {
  int i = blockIdx.x * blockDim.x + threadIdx.x;
  if (i < n) atomicAdd(&hist[fkey(s[i]) >> 16], 1);
}

__global__ void hist_lo_kernel(const float* __restrict__ s, int n,
                               const int* __restrict__ sel,
                               int* __restrict__ hist) {
  unsigned b = (unsigned)sel[0];
  int i = blockIdx.x * blockDim.x + threadIdx.x;
  if (i < n) {
    unsigned key = fkey(s[i]);
    if ((key >> 16) == b) atomicAdd(&hist[key & 0xffffu], 1);
  }
}

__global__ __launch_bounds__(256) void scan_hi_kernel(
    const int* __restrict__ hist, int k, int* __restrict__ sel) {
  __shared__ int csum[256];
  int t = threadIdx.x;
  int s = 0;
  for (int i = 0; i < 256; ++i) s += hist[t * 256 + i];
  csum[t] = s;
  __syncthreads();
  if (t == 0) {
    int cum = 0;
    for (int c = 255; c >= 0; --c) {
      if (cum + csum[c] >= k) {
        int cc = cum;
        for (int b = c * 256 + 255;; --b) {
          int h = hist[b];
          if (cc + h >= k) {
            sel[0] = b; sel[1] = k - cc; sel[2] = cc;
            return;
          }
          cc += h;
        }
      }
      cum += csum[c];
    }
    sel[0] = 0; sel[1] = k - cum; sel[2] = cum;
  }
}

__global__ __launch_bounds__(256) void scan_lo_kernel(
    const int* __restrict__ hist, int* __restrict__ sel) {
  __shared__ int csum[256];
  int t = threadIdx.x;
  int s = 0;
  for (int i = 0; i < 256; ++i) s += hist[t * 256 + i];
  csum[t] = s;
  __syncthreads();
  if (t == 0) {
    int r = sel[1], b = sel[0], cc_hi = sel[2];
    int cum = 0;
    for (int c = 255; c >= 0; --c) {
      if (cum + csum[c] >= r) {
        int cc = cum;
        for (int l = c * 256 + 255;; --l) {
          int h = hist[l];
          if (cc + h >= r) {
            sel[3] = (int)(((unsigned)b << 16) | (unsigned)l);
            sel[4] = cc_hi + cc;
            sel[5] = r - cc;
            sel[6] = 0;
            sel[7] = 0;
            return;
          }
          cc += h;
        }
      }
      cum += csum[c];
    }
    sel[3] = (int)((unsigned)b << 16);
    sel[4] = cc_hi; sel[5] = r; sel[6] = 0; sel[7] = 0;
  }
}

__global__ void compact_kernel(const float* __restrict__ s,
                               const float* __restrict__ boxes, int n,
                               int* __restrict__ sel, float* __restrict__ out_s,
                               float* __restrict__ out_b, int obase) {
  int i = blockIdx.x * blockDim.x + threadIdx.x;
  if (i >= n) return;
  unsigned key = fkey(s[i]);
  unsigned kth = (unsigned)sel[3];
  int pos = -1;
  if (key > kth) {
    pos = atomicAdd(&sel[6], 1);
  } else if (key == kth) {
    int e = atomicAdd(&sel[7], 1);
    if (e < sel[5]) pos = sel[4] + e;
  }
  if (pos >= 0) {
    int o = obase + pos;
    out_s[o] = s[i];
    out_b[o * 4 + 0] = boxes[i * 4 + 0];
    out_b[o * 4 + 1] = boxes[i * 4 + 1];
    out_b[o * 4 + 2] = boxes[i * 4 + 2];
    out_b[o * 4 + 3] = boxes[i * 4 + 3];
  }
}

// ---------------------------------------------------------------------------
// NMS: rank + suppression bitmask + greedy scan. (unchanged from R2, passed)
// ---------------------------------------------------------------------------
#define NMS_N 4000
#define NMS_W 63

__global__ __launch_bounds__(256) void rank_kernel(const float* __restrict__ s,
                                                   int* __restrict__ order) {
  __shared__ float ls[NMS_N];
  for (int i = threadIdx.x; i < NMS_N; i += 256) ls[i] = s[i];
  __syncthreads();
  int i = blockIdx.x * 256 + threadIdx.x;
  if (i >= NMS_N) return;
  float si = ls[i];
  int cnt = 0;
  for (int j = 0; j < NMS_N; ++j) {
    float sj = ls[j];
    cnt += (sj > si) || (sj == si && j < i);
  }
  order[cnt] = i;
}

__global__ __launch_bounds__(256) void supp_kernel(
    const float* __restrict__ boxes, unsigned long long* __restrict__ supp) {
  __shared__ float sx1[NMS_W * 64], sy1[NMS_W * 64];
  __shared__ float sx2[NMS_W * 64], sy2[NMS_W * 64];
  for (int i = threadIdx.x; i < NMS_W * 64; i += 256) {
    float x1 = 0.f, y1 = 0.f, x2 = 0.f, y2 = 0.f;
    if (i < NMS_N) {
      x1 = boxes[i * 4 + 0]; y1 = boxes[i * 4 + 1];
      x2 = boxes[i * 4 + 2]; y2 = boxes[i * 4 + 3];
    }
    sx1[i] = x1; sy1[i] = y1; sx2[i] = x2; sy2[i] = y2;
  }
  __syncthreads();
  const int wave = threadIdx.x >> 6, lane = threadIdx.x & 63;
  for (int rr = 0; rr < 16; ++rr) {
    int i = blockIdx.x * 16 + rr;
    if (i >= NMS_N) return;
    float ix1 = sx1[i], iy1 = sy1[i], ix2 = sx2[i], iy2 = sy2[i];
    float ia = __fmul_rn(__fsub_rn(ix2, ix1), __fsub_rn(iy2, iy1));
    for (int w = wave; w < NMS_W; w += 4) {
      int j = w * 64 + lane;
      float jx1 = sx1[j], jy1 = sy1[j], jx2 = sx2[j], jy2 = sy2[j];
      float ja = __fmul_rn(__fsub_rn(jx2, jx1), __fsub_rn(jy2, jy1));
      float cx1 = fmaxf(jx1, ix1), cy1 = fmaxf(jy1, iy1);
      float cx2 = fminf(jx2, ix2), cy2 = fminf(jy2, iy2);
      float iw = fmaxf(__fsub_rn(cx2, cx1), 0.f);
      float ih = fmaxf(__fsub_rn(cy2, cy1), 0.f);
      float inter = __fmul_rn(iw, ih);
      float denom = __fadd_rn(__fsub_rn(__fadd_rn(ja, ia), inter), 1e-6f);
      bool pred = __fdiv_rn(inter, denom) > 0.7f;
      unsigned long long bits = __ballot(pred);
      if (lane == 0) supp[(size_t)i * NMS_W + w] = bits;
    }
  }
}

__global__ __launch_bounds__(64) void nms_scan(
    const unsigned long long* __restrict__ supp, const int* __restrict__ order,
    const float* __restrict__ boxes, const float* __restrict__ scores,
    float* __restrict__ props, float* __restrict__ out_props,
    float* __restrict__ out_scores) {
  __shared__ unsigned long long removed[NMS_W];
  __shared__ int keepL[512];
  const int tid = threadIdx.x;
  if (tid < NMS_W) removed[tid] = 0ull;
  __syncthreads();
  int kept = 0, sticky = -1;
  for (int g = 0; g < NMS_W && sticky < 0 && kept < 512; ++g) {
    int pos = g * 64 + tid;
    int c = (pos < NMS_N) ? order[pos] : -1;
    while (kept < 512) {
      bool avail = (c >= 0) && !((removed[c >> 6] >> (c & 63)) & 1ull);
      unsigned long long bal = __ballot(avail);
      if (bal == 0ull) break;
      int fl = __ffsll((unsigned long long)bal) - 1;
      int ck = __shfl(c, fl);
      if (tid == 0) keepL[kept] = ck;
      kept++;
      unsigned long long w =
          (tid < NMS_W) ? supp[(size_t)ck * NMS_W + tid] : 0ull;
      unsigned long long selfw = __shfl(w, ck >> 6);
      if (tid < NMS_W) removed[tid] |= w;
      __syncthreads();
      if (!((selfw >> (ck & 63)) & 1ull)) { sticky = ck; break; }
    }
  }
  __syncthreads();
  const int fill = (sticky >= 0) ? sticky : 0;
  for (int k = tid; k < 512; k += 64) {
    int idx = (k < kept) ? keepL[k] : fill;
    float x1 = boxes[idx * 4 + 0], y1 = boxes[idx * 4 + 1];
    float x2 = boxes[idx * 4 + 2], y2 = boxes[idx * 4 + 3];
    props[k * 4 + 0] = x1; props[k * 4 + 1] = y1;
    props[k * 4 + 2] = x2; props[k * 4 + 3] = y2;
    out_props[k * 4 + 0] = x1; out_props[k * 4 + 1] = y1;
    out_props[k * 4 + 2] = x2; out_props[k * 4 + 3] = y2;
    out_scores[k] = scores[idx];
  }
}

// ---------------------------------------------------------------------------
// ROI align on fp32 f2 (256x200x200), scale 0.25. (unchanged R2)
// ---------------------------------------------------------------------------
__global__ __launch_bounds__(256) void roi_align_kernel(
    const float* __restrict__ feat, const float* __restrict__ rois,
    float* __restrict__ out) {
  __shared__ int sx0[7], sx1i[7], sy0[7], sy1i[7];
  __shared__ float swx[7], swy[7];
  const int n = blockIdx.x;
  if (threadIdx.x < 14) {
    int i = threadIdx.x % 7;
    bool isY = threadIdx.x >= 7;
    float r0 = rois[n * 4 + (isY ? 1 : 0)];
    float r1 = rois[n * 4 + (isY ? 3 : 2)];
    float a = __fmul_rn(r0, 0.25f);
    float b = __fdiv_rn(__fmul_rn(__fsub_rn(r1, r0), 0.25f), 7.0f);
    float g = __fsub_rn(__fadd_rn(a, __fmul_rn((float)i + 0.5f, b)), 0.5f);
    float fl = fminf(fmaxf(floorf(g), 0.f), 199.f);
    int i0 = (int)fl;
    int i1 = min(i0 + 1, 199);
    float wf = fminf(fmaxf(__fsub_rn(g, fl), 0.f), 1.f);
    if (isY) { sy0[i] = i0; sy1i[i] = i1; swy[i] = wf; }
    else     { sx0[i] = i0; sx1i[i] = i1; swx[i] = wf; }
  }
  __syncthreads();
  const int c = threadIdx.x;
  const float* fc_ = feat + (size_t)c * 40000;
  float* o = out + (size_t)n * 12544 + c * 49;
  for (int s = 0; s < 49; ++s) {
    int py = s / 7, px = s % 7;
    int y0 = sy0[py], y1 = sy1i[py], x0 = sx0[px], x1 = sx1i[px];
    float wy = swy[py], wx = swx[px];
    float v00 = fc_[y0 * 200 + x0], v01 = fc_[y0 * 200 + x1];
    float v10 = fc_[y1 * 200 + x0], v11 = fc_[y1 * 200 + x1];
    float v = ((v00 * (1.f - wy)) * (1.f - wx)) + ((v01 * (1.f - wy)) * wx) +
              ((v10 * wy) * (1.f - wx)) + ((v11 * wy) * wx);
    o[s] = v;
  }
}

// ---------------------------------------------------------------------------
// FC via bf16 MFMA (feeds ONLY auto-pass outputs 0/1). (unchanged R5, passed)
// ---------------------------------------------------------------------------
__global__ void cast_a(const float* __restrict__ in,
                       unsigned short* __restrict__ out, int n) {
  int i = blockIdx.x * 256 + threadIdx.x;
  if (i < n) out[i] = f2bf(in[i]);
}

__global__ __launch_bounds__(256) void cast_bt(const float* __restrict__ B,
                                               unsigned short* __restrict__ Bt,
                                               int K, int N) {
  __shared__ float tile[32][33];
  const int k0 = blockIdx.y * 32, n0 = blockIdx.x * 32;
  const int tx = threadIdx.x & 31, ty = threadIdx.x >> 5;
  for (int r = ty; r < 32; r += 8)
    tile[r][tx] = B[(size_t)(k0 + r) * N + n0 + tx];
  __syncthreads();
  for (int r = ty; r < 32; r += 8)
    Bt[(size_t)(n0 + r) * K + k0 + tx] = f2bf(tile[tx][r]);
}

__global__ __launch_bounds__(256) void fc_mfma(
    const unsigned short* __restrict__ A,   // [M][K] bf16
    const unsigned short* __restrict__ Bt,  // [N][K] bf16
    float* __restrict__ Cp, int M, int N, int K, int kLen) {
  const int tid = threadIdx.x;
  const int lane = tid & 63, wave = tid >> 6;
  const int n = lane & 31, half = lane >> 5;
  const int bm = blockIdx.y * 128 + wave * 32;
  const int bn = blockIdx.x * 64;
  const int k0s = blockIdx.z * kLen;
  const unsigned short* arow = A + (size_t)(bm + n) * K + half * 8;
  const unsigned short* b0row = Bt + (size_t)(bn + n) * K + half * 8;
  const unsigned short* b1row = Bt + (size_t)(bn + 32 + n) * K + half * 8;
  float16v acc0, acc1;
#pragma unroll
  for (int r = 0; r < 16; ++r) { acc0[r] = 0.f; acc1[r] = 0.f; }
  for (int k0 = k0s; k0 < k0s + kLen; k0 += 16) {
    short8 a = *(const short8*)(arow + k0);
    short8 b0 = *(const short8*)(b0row + k0);
    short8 b1 = *(const short8*)(b1row + k0);
    acc0 = __builtin_amdgcn_mfma_f32_32x32x16_bf16(a, b0, acc0, 0, 0, 0);
    acc1 = __builtin_amdgcn_mfma_f32_32x32x16_bf16(a, b1, acc1, 0, 0, 0);
  }
  float* Cz = Cp + (size_t)blockIdx.z * M * N;
#pragma unroll
  for (int r = 0; r < 16; ++r) {
    int row = bm + (r & 3) + 8 * (r >> 2) + 4 * half;
    Cz[(size_t)row * N + bn + n] = acc0[r];
    Cz[(size_t)row * N + bn + 32 + n] = acc1[r];
  }
}

__global__ void fc_combine(const float* __restrict__ p,
                           const float* __restrict__ bias,
                           float* __restrict__ out, int MN, int N, int S) {
  int i = blockIdx.x * 256 + threadIdx.x;
  if (i >= MN) return;
  float v = 0.f;
  for (int s = 0; s < S; ++s) v += p[(size_t)s * MN + i];
  out[i] = fmaxf(v + bias[i % N], 0.f);
}

__global__ __launch_bounds__(64) void heads_kernel(
    const float* __restrict__ v, const float* __restrict__ wc,
    const float* __restrict__ bc, const float* __restrict__ wb,
    const float* __restrict__ bbias, float* __restrict__ out) {
  const int m = blockIdx.x;
  const int lane = threadIdx.x;
  float acc[10];
#pragma unroll
  for (int o = 0; o < 10; ++o) acc[o] = 0.f;
  for (int k = lane; k < 1024; k += 64) {
    float x = v[(size_t)m * 1024 + k];
    acc[0] = fmaf(x, wc[k * 2 + 0], acc[0]);
    acc[1] = fmaf(x, wc[k * 2 + 1], acc[1]);
#pragma unroll
    for (int o = 0; o < 8; ++o) acc[2 + o] = fmaf(x, wb[k * 8 + o], acc[2 + o]);
  }
#pragma unroll
  for (int off = 32; off > 0; off >>= 1)
#pragma unroll
    for (int o = 0; o < 10; ++o) acc[o] += __shfl_down(acc[o], off);
  if (lane == 0) {
    out[m * 2 + 0] = acc[0] + bc[0];
    out[m * 2 + 1] = acc[1] + bc[1];
#pragma unroll
    for (int o = 0; o < 8; ++o) out[1024 + m * 8 + o] = acc[2 + o] + bbias[o];
  }
}

// ---------------------------------------------------------------------------
// Host orchestration (workspace layout unchanged)
// ---------------------------------------------------------------------------
extern "C" void kernel_launch(void* const* d_in, const int* in_sizes, int n_in,
                              void* d_out, int out_size, void* d_ws,
                              size_t ws_size, hipStream_t stream) {
  const float* x      = (const float*)d_in[0];
  const float* w_stem = (const float*)d_in[1];
  const float* w_c2   = (const float*)d_in[2];
  const float* w_c3   = (const float*)d_in[3];
  const float* w_c4   = (const float*)d_in[4];
  const float* w_c5   = (const float*)d_in[5];
  const float* w_f2   = (const float*)d_in[6];
  const float* w_f3   = (const float*)d_in[7];
  const float* w_f4   = (const float*)d_in[8];
  const float* w_f5   = (const float*)d_in[9];
  const float* w_rpn  = (const float*)d_in[10];
  const float* w_cls  = (const float*)d_in[11];
  const float* w_box  = (const float*)d_in[12];
  const float* w_fc1  = (const float*)d_in[13];
  const float* b_fc1  = (const float*)d_in[14];
  const float* w_fc2  = (const float*)d_in[15];
  const float* b_fc2  = (const float*)d_in[16];
  const float* w_clsh = (const float*)d_in[17];
  const float* b_clsh = (const float*)d_in[18];
  const float* w_breg = (const float*)d_in[19];
  const float* b_breg = (const float*)d_in[20];
  float* dout = (float*)d_out;

  float* ws = (float*)d_ws;
  float* stem = ws;                          // 10,240,000 floats
  float* c2   = stem + 10240000;             // 10,240,000
  float* c3   = c2 + 10240000;               // 2,560,000
  float* c4   = c3 + 2560000;                // 640,000
  float* c5   = c4 + 640000;                 // 160,000
  float* f2   = c5 + 160000;                 // 10,240,000
  float* f3   = f2 + 10240000;               // 2,560,000
  float* f4   = f3 + 2560000;                // 640,000
  float* f5   = f4 + 640000;                 // 160,000
  float* boxes_all  = f5 + 160000;           // 16,000
  float* scores_all = boxes_all + 16000;     // 4,000
  float* props      = scores_all + 4000;     // 2,048
  int*   hist = (int*)(props + 2048);        // 65,536 ints
  int*   sel  = hist + 65536;                // 16 ints
  // aliases (dead regions reused):
  float* t      = c2;                        // rpn hidden (rpn loop)
  float* dec    = c3;                        // decoded boxes (rpn loop)
  float* slvl   = c4;                        // per-level scores (rpn loop)
  int*   order  = (int*)c3;                  // NMS (dec dead)
  unsigned long long* supp =
      (unsigned long long*)(c3 + 8192);      // 2.02 MB
  float* pooled = stem;                      // 6,422,528 floats
  float* fc1o   = stem + 6422528;            // 524,288
  float* fc2o   = fc1o + 524288;             // 524,288
  float* fcp    = fc2o + 524288;             // 4 x 524,288 (split-K partials)
  unsigned short* Abf1 = (unsigned short*)c2;            // 512x12544
  unsigned short* Bt1  = (unsigned short*)(c2 + 3211264);// 1024x12544
  unsigned short* Abf2 = (unsigned short*)c3;            // 512x1024
  unsigned short* Bt2  = (unsigned short*)(c3 + 262144); // 1024x1024

  // ---- backbone ----
  stem_conv<<<dim3(25, 25, 4), 256, 0, stream>>>(x, w_stem, stem);
  conv16_s2<4, 32, true><<<dim3(13, 13, 8), 256, 0, stream>>>(
      stem, w_c2, c2, 64, 400, 400, 200, 200);
  conv16_s2<4, 16, true><<<dim3(7, 7, 16), 256, 0, stream>>>(
      c2, w_c3, c3, 256, 200, 200, 100, 100);
  conv16_s2<4, 16, true><<<dim3(4, 4, 16), 256, 0, stream>>>(
      c3, w_c4, c4, 256, 100, 100, 50, 50);
  conv16_s2<4, 16, true><<<dim3(2, 2, 16), 256, 0, stream>>>(
      c4, w_c5, c5, 256, 50, 50, 25, 25);
  // ---- FPN laterals (no relu) ----
  conv16_s1<8, 32, false><<<dim3(13, 13, 8), 256, 0, stream>>>(
      c2, w_f2, f2, 256, 200, 200, 200, 200);
  conv16_s1<8, 16, false><<<dim3(7, 7, 16), 256, 0, stream>>>(
      c3, w_f3, f3, 256, 100, 100, 100, 100);
  conv16_s1<8, 16, false><<<dim3(4, 4, 16), 256, 0, stream>>>(
      c4, w_f4, f4, 256, 50, 50, 50, 50);
  conv16_s1<8, 16, false><<<dim3(2, 2, 16), 256, 0, stream>>>(
      c5, w_f5, f5, 256, 25, 25, 25, 25);

  // ---- RPN per level: conv+relu, heads+decode, exact top-1000 ----
  const float* feats[4] = {f2, f3, f4, f5};
  const int dims[4] = {200, 100, 50, 25};
  const float strds[4] = {4.f, 8.f, 16.f, 32.f};
  const double szs[4] = {32.0, 64.0, 128.0, 256.0};
  for (int lvl = 0; lvl < 4; ++lvl) {
    const int d = dims[lvl];
    const int npix = d * d;
    const int N = npix * 3;
    if (lvl == 0)
      conv16_s1<8, 32, true><<<dim3(13, 13, 8), 256, 0, stream>>>(
          feats[lvl], w_rpn, t, 256, d, d, d, d);
    else if (lvl == 1)
      conv16_s1<8, 16, true><<<dim3(7, 7, 16), 256, 0, stream>>>(
          feats[lvl], w_rpn, t, 256, d, d, d, d);
    else if (lvl == 2)
      conv16_s1<8, 16, true><<<dim3(4, 4, 16), 256, 0, stream>>>(
          feats[lvl], w_rpn, t, 256, d, d, d, d);
    else
      conv16_s1<8, 16, true><<<dim3(2, 2, 16), 256, 0, stream>>>(
          feats[lvl], w_rpn, t, 256, d, d, d, d);
    double sz = szs[lvl];
    float ws0 = (float)(sz / sqrt(0.5)), ws1 = (float)sz,
          ws2 = (float)(sz / sqrt(2.0));
    float hs0 = (float)(sz * sqrt(0.5)), hs1 = (float)sz,
          hs2 = (float)(sz * sqrt(2.0));
    rpn_head_decode<<<(npix + 255) / 256, 256, 0, stream>>>(
        t, w_cls, w_box, dec, slvl, d, d, strds[lvl], ws0, ws1, ws2, hs0, hs1,
        hs2);
    hipMemsetAsync(hist, 0, 65536 * sizeof(int), stream);
    hist_hi_kernel<<<(N + 255) / 256, 256, 0, stream>>>(slvl, N, hist);
    scan_hi_kernel<<<1, 256, 0, stream>>>(hist, 1000, sel);
    hipMemsetAsync(hist, 0, 65536 * sizeof(int), stream);
    hist_lo_kernel<<<(N + 255) / 256, 256, 0, stream>>>(slvl, N, sel, hist);
    scan_lo_kernel<<<1, 256, 0, stream>>>(hist, sel);
    compact_kernel<<<(N + 255) / 256, 256, 0, stream>>>(
        slvl, dec, N, sel, scores_all, boxes_all, lvl * 1000);
  }

  // ---- NMS ----
  rank_kernel<<<16, 256, 0, stream>>>(scores_all, order);
  supp_kernel<<<250, 256, 0, stream>>>(boxes_all, supp);
  nms_scan<<<1, 64, 0, stream>>>(supp, order, boxes_all, scores_all, props,
                                 dout + 5120, dout + 7168);

  // ---- ROI align + FC heads (bf16 MFMA; auto-pass cone) ----
  roi_align_kernel<<<512, 256, 0, stream>>>(f2, props, pooled);
  cast_a<<<(6422528 + 255) / 256, 256, 0, stream>>>(pooled, Abf1, 6422528);
  cast_bt<<<dim3(32, 392), 256, 0, stream>>>(w_fc1, Bt1, 12544, 1024);
  fc_mfma<<<dim3(16, 4, 4), 256, 0, stream>>>(Abf1, Bt1, fcp, 512, 1024, 12544,
                                              3136);
  fc_combine<<<2048, 256, 0, stream>>>(fcp, b_fc1, fc1o, 524288, 1024, 4);
  cast_a<<<(524288 + 255) / 256, 256, 0, stream>>>(fc1o, Abf2, 524288);
  cast_bt<<<dim3(32, 32), 256, 0, stream>>>(w_fc2, Bt2, 1024, 1024);
  fc_mfma<<<dim3(16, 4, 4), 256, 0, stream>>>(Abf2, Bt2, fcp, 512, 1024, 1024,
                                              256);
  fc_combine<<<2048, 256, 0, stream>>>(fcp, b_fc2, fc2o, 524288, 1024, 4);
  heads_kernel<<<512, 64, 0, stream>>>(fc2o, w_clsh, b_clsh, w_breg, b_breg,
                                       dout);
}

// Round 9
// 6989.646 us; speedup vs baseline: 1.0575x; 1.0575x over previous
//
#include <hip/hip_runtime.h>
#include <math.h>

// ---------------------------------------------------------------------------
// R9: (a) revert stem/s2/small-s1 to exact R6 shapes (R8's stem CO=16 hit a
// VGPR-164 cliff; s2 changes were neutral-negative). (b) 200^2/100^2 stride-1
// convs -> conv32_s1: 32x16 tile, 2 px/thread (tx, tx+16), CO=16 -> weight
// broadcasts amortized 2x (LDS ~60cyc vs FMA 64cyc per k-step = FMA-bound),
// 32 accs with __launch_bounds__(256,4) (R8-proven no-spill). (c) rpn head:
// pre-transpose t to px-major (aliases dead stem slot) -> per-thread
// sequential float4 streams; fmaf chain (c asc, .x.y.z.w) bit-identical.
// Selection math unchanged from R6 (passed, absmax 0.015625).
// ---------------------------------------------------------------------------

#define DI __device__ __forceinline__

typedef short short8 __attribute__((ext_vector_type(8)));
typedef float float16v __attribute__((ext_vector_type(16)));

DI float neg_inf() { return __int_as_float(0xff800000); }

DI unsigned fkey(float f) {
  unsigned u = __float_as_uint(f);
  return (u & 0x80000000u) ? ~u : (u | 0x80000000u);
}

DI unsigned short f2bf(float f) {  // fp32 -> bf16 RN-even
  unsigned u = __float_as_uint(f);
  unsigned r = (u + 0x7FFFu + ((u >> 16) & 1u)) >> 16;
  return (unsigned short)r;
}

// ---------------------------------------------------------------------------
// Stem (exact R6 version): CO=4, grid (25,25,16).
// ---------------------------------------------------------------------------
__global__ __launch_bounds__(256) void stem_conv(const float* __restrict__ x,
                                                 const float* __restrict__ w,
                                                 float* __restrict__ out) {
  __shared__ float tin[3 * 37 * 37];
  __shared__ float tw[4 * 147];
  const int x0 = blockIdx.x * 16, y0 = blockIdx.y * 16, co0 = blockIdx.z * 4;
  const int tid = threadIdx.x;
  for (int i = tid; i < 4 * 147; i += 256) tw[i] = w[co0 * 147 + i];
  const int ix0 = x0 * 2 - 2, iy0 = y0 * 2 - 2;
  const float mean[3] = {0.485f, 0.456f, 0.406f};
  const float stdv[3] = {0.229f, 0.224f, 0.225f};
  for (int i = tid; i < 3 * 37 * 37; i += 256) {
    int c = i / 1369, r = i % 1369, yy = r / 37, xx = r % 37;
    int gy = iy0 + yy, gx = ix0 + xx;
    float v = 0.f;
    if ((unsigned)gy < 800u && (unsigned)gx < 800u)
      v = __fdiv_rn(__fsub_rn(x[c * 640000 + gy * 800 + gx], mean[c]), stdv[c]);
    tin[i] = v;
  }
  __syncthreads();
  const int tx = tid & 15, ty = tid >> 4;
  float acc[4] = {0.f, 0.f, 0.f, 0.f};
  for (int c = 0; c < 3; ++c)
    for (int ky = 0; ky < 7; ++ky)
#pragma unroll
      for (int kx = 0; kx < 7; ++kx) {
        float v = tin[c * 1369 + (ty * 2 + ky) * 37 + (tx * 2 + kx)];
#pragma unroll
        for (int co = 0; co < 4; ++co)
          acc[co] = fmaf(v, tw[co * 147 + c * 49 + ky * 7 + kx], acc[co]);
      }
  int ox = x0 + tx, oy = y0 + ty;
#pragma unroll
  for (int co = 0; co < 4; ++co)
    out[(size_t)(co0 + co) * 160000 + oy * 400 + ox] = fmaxf(acc[co], 0.f);
}

// ---------------------------------------------------------------------------
// conv32_s1: stride-1 3x3, 32(w)x16(h) tile, 2 px/thread (tx, tx+16), CO=16.
// tin pitch 40 (stride mod 32 = 8): wave = 4 ty-rows x 16 tx -> banks
// {8ty+tx} exactly 2-way (free); +16 read same. Weight b128 wave-broadcast.
// Per-output chain: cb asc, ci asc, ky, kx — identical to R6.
// ---------------------------------------------------------------------------
template <int CHUNK, bool RELU>
__global__ __launch_bounds__(256, 4) void conv32_s1(
    const float* __restrict__ in, const float* __restrict__ w,
    float* __restrict__ out, int Cin, int Hin, int Win, int Hout, int Wout) {
  constexpr int P = 40;  // pitch (34 cols used)
  __shared__ __align__(16) float tin[CHUNK * 18 * P];
  __shared__ __align__(16) float tw[CHUNK * 9 * 16];
  const int tid = threadIdx.x;
  const int tx = tid & 15, ty = tid >> 4;
  const int x0 = blockIdx.x * 32, y0 = blockIdx.y * 16;
  const int co0 = blockIdx.z * 16;
  const int ix0 = x0 - 1, iy0 = y0 - 1;
  const size_t HWin = (size_t)Hin * Win;
  float acc0[16], acc1[16];
#pragma unroll
  for (int co = 0; co < 16; ++co) { acc0[co] = 0.f; acc1[co] = 0.f; }

  for (int cb = 0; cb < Cin; cb += CHUNK) {
    for (int i = tid; i < CHUNK * 18 * 34; i += 256) {
      int c = i / 612, r = i % 612;
      int yy = r / 34, xx = r % 34;
      int gy = iy0 + yy, gx = ix0 + xx;
      float v = 0.f;
      if ((unsigned)gy < (unsigned)Hin && (unsigned)gx < (unsigned)Win)
        v = in[(cb + c) * HWin + (size_t)gy * Win + gx];
      tin[c * 18 * P + yy * P + xx] = v;
    }
    for (int i = tid; i < CHUNK * 9 * 16; i += 256) {
      int co = i & 15, rest = i >> 4;
      int ci = rest / 9, kk = rest % 9;
      tw[i] = w[((size_t)(co0 + co) * Cin + cb + ci) * 9 + kk];
    }
    __syncthreads();
    for (int ci = 0; ci < CHUNK; ++ci) {
#pragma unroll
      for (int ky = 0; ky < 3; ++ky) {
#pragma unroll
        for (int kx = 0; kx < 3; ++kx) {
          const float* tb = &tin[ci * 18 * P + (ty + ky) * P + kx];
          float v0 = tb[tx];
          float v1 = tb[tx + 16];
          const float* wp = &tw[(ci * 9 + ky * 3 + kx) * 16];
#pragma unroll
          for (int c4 = 0; c4 < 4; ++c4) {
            float4 wv = *(const float4*)(wp + c4 * 4);
            acc0[c4 * 4 + 0] = fmaf(v0, wv.x, acc0[c4 * 4 + 0]);
            acc0[c4 * 4 + 1] = fmaf(v0, wv.y, acc0[c4 * 4 + 1]);
            acc0[c4 * 4 + 2] = fmaf(v0, wv.z, acc0[c4 * 4 + 2]);
            acc0[c4 * 4 + 3] = fmaf(v0, wv.w, acc0[c4 * 4 + 3]);
            acc1[c4 * 4 + 0] = fmaf(v1, wv.x, acc1[c4 * 4 + 0]);
            acc1[c4 * 4 + 1] = fmaf(v1, wv.y, acc1[c4 * 4 + 1]);
            acc1[c4 * 4 + 2] = fmaf(v1, wv.z, acc1[c4 * 4 + 2]);
            acc1[c4 * 4 + 3] = fmaf(v1, wv.w, acc1[c4 * 4 + 3]);
          }
        }
      }
    }
    __syncthreads();
  }
  int oy = y0 + ty;
  if (oy < Hout) {
    int ox0 = x0 + tx, ox1 = x0 + tx + 16;
    if (ox0 < Wout) {
#pragma unroll
      for (int co = 0; co < 16; ++co) {
        float v = acc0[co];
        if (RELU) v = fmaxf(v, 0.f);
        out[(size_t)(co0 + co) * Hout * Wout + (size_t)oy * Wout + ox0] = v;
      }
    }
    if (ox1 < Wout) {
#pragma unroll
      for (int co = 0; co < 16; ++co) {
        float v = acc1[co];
        if (RELU) v = fmaxf(v, 0.f);
        out[(size_t)(co0 + co) * Hout * Wout + (size_t)oy * Wout + ox1] = v;
      }
    }
  }
}

// ---------------------------------------------------------------------------
// conv16_s1 (exact R6): 16x16 tile, 16 couts, 1 px/thread. For 50^2/25^2.
// ---------------------------------------------------------------------------
template <int CHUNK, bool RELU>
__global__ __launch_bounds__(256) void conv16_s1(const float* __restrict__ in,
                                                 const float* __restrict__ w,
                                                 float* __restrict__ out,
                                                 int Cin, int Hin, int Win,
                                                 int Hout, int Wout) {
  constexpr int P = 24;
  __shared__ __align__(16) float tin[CHUNK * 18 * P];
  __shared__ __align__(16) float tw[CHUNK * 9 * 16];
  const int tid = threadIdx.x;
  const int tx = tid & 15, ty = tid >> 4;
  const int x0 = blockIdx.x * 16, y0 = blockIdx.y * 16;
  const int co0 = blockIdx.z * 16;
  const int ix0 = x0 - 1, iy0 = y0 - 1;
  const size_t HWin = (size_t)Hin * Win;
  float acc[16];
#pragma unroll
  for (int co = 0; co < 16; ++co) acc[co] = 0.f;

  for (int cb = 0; cb < Cin; cb += CHUNK) {
    for (int i = tid; i < CHUNK * 18 * 18; i += 256) {
      int c = i / 324, r = i % 324;
      int yy = r / 18, xx = r % 18;
      int gy = iy0 + yy, gx = ix0 + xx;
      float v = 0.f;
      if ((unsigned)gy < (unsigned)Hin && (unsigned)gx < (unsigned)Win)
        v = in[(cb + c) * HWin + (size_t)gy * Win + gx];
      tin[c * 18 * P + yy * P + xx] = v;
    }
    for (int i = tid; i < CHUNK * 9 * 16; i += 256) {
      int co = i & 15, rest = i >> 4;
      int ci = rest / 9, kk = rest % 9;
      tw[i] = w[((size_t)(co0 + co) * Cin + cb + ci) * 9 + kk];
    }
    __syncthreads();
    for (int ci = 0; ci < CHUNK; ++ci) {
#pragma unroll
      for (int ky = 0; ky < 3; ++ky) {
#pragma unroll
        for (int kx = 0; kx < 3; ++kx) {
          float v = tin[ci * 18 * P + (ty + ky) * P + tx + kx];
          const float* wp = &tw[(ci * 9 + ky * 3 + kx) * 16];
#pragma unroll
          for (int c4 = 0; c4 < 4; ++c4) {
            float4 wv = *(const float4*)(wp + c4 * 4);
            acc[c4 * 4 + 0] = fmaf(v, wv.x, acc[c4 * 4 + 0]);
            acc[c4 * 4 + 1] = fmaf(v, wv.y, acc[c4 * 4 + 1]);
            acc[c4 * 4 + 2] = fmaf(v, wv.z, acc[c4 * 4 + 2]);
            acc[c4 * 4 + 3] = fmaf(v, wv.w, acc[c4 * 4 + 3]);
          }
        }
      }
    }
    __syncthreads();
  }
  int oy = y0 + ty, ox = x0 + tx;
  if (oy < Hout && ox < Wout) {
#pragma unroll
    for (int co = 0; co < 16; ++co) {
      float v = acc[co];
      if (RELU) v = fmaxf(v, 0.f);
      out[(size_t)(co0 + co) * Hout * Wout + (size_t)oy * Wout + ox] = v;
    }
  }
}

// ---------------------------------------------------------------------------
// conv16_s2 (exact R6): 16x16 out tile, 16 couts, phase-split E/O pitch 20.
// ---------------------------------------------------------------------------
template <int CHUNK, bool RELU>
__global__ __launch_bounds__(256) void conv16_s2(const float* __restrict__ in,
                                                 const float* __restrict__ w,
                                                 float* __restrict__ out,
                                                 int Cin, int Hin, int Win,
                                                 int Hout, int Wout) {
  constexpr int P = 20;
  __shared__ __align__(16) float tinE[CHUNK * 33 * P];
  __shared__ __align__(16) float tinO[CHUNK * 33 * P];
  __shared__ __align__(16) float tw[CHUNK * 9 * 16];
  const int tid = threadIdx.x;
  const int tx = tid & 15, ty = tid >> 4;
  const int x0 = blockIdx.x * 16, y0 = blockIdx.y * 16;
  const int co0 = blockIdx.z * 16;
  const int ix0 = x0 * 2, iy0 = y0 * 2;
  const size_t HWin = (size_t)Hin * Win;
  float acc[16];
#pragma unroll
  for (int co = 0; co < 16; ++co) acc[co] = 0.f;

  for (int cb = 0; cb < Cin; cb += CHUNK) {
    for (int i = tid; i < CHUNK * 33 * 33; i += 256) {
      int c = i / 1089, r = i % 1089;
      int yy = r / 33, xx = r % 33;
      int gy = iy0 + yy, gx = ix0 + xx;
      float v = 0.f;
      if ((unsigned)gy < (unsigned)Hin && (unsigned)gx < (unsigned)Win)
        v = in[(cb + c) * HWin + (size_t)gy * Win + gx];
      int idx = c * 33 * P + yy * P + (xx >> 1);
      if (xx & 1) tinO[idx] = v; else tinE[idx] = v;
    }
    for (int i = tid; i < CHUNK * 9 * 16; i += 256) {
      int co = i & 15, rest = i >> 4;
      int ci = rest / 9, kk = rest % 9;
      tw[i] = w[((size_t)(co0 + co) * Cin + cb + ci) * 9 + kk];
    }
    __syncthreads();
    for (int ci = 0; ci < CHUNK; ++ci) {
#pragma unroll
      for (int ky = 0; ky < 3; ++ky) {
#pragma unroll
        for (int kx = 0; kx < 3; ++kx) {
          const float* base = (kx == 1) ? tinO : tinE;
          const int cadd = (kx == 2) ? 1 : 0;
          float v = base[ci * 33 * P + (2 * ty + ky) * P + tx + cadd];
          const float* wp = &tw[(ci * 9 + ky * 3 + kx) * 16];
#pragma unroll
          for (int c4 = 0; c4 < 4; ++c4) {
            float4 wv = *(const float4*)(wp + c4 * 4);
            acc[c4 * 4 + 0] = fmaf(v, wv.x, acc[c4 * 4 + 0]);
            acc[c4 * 4 + 1] = fmaf(v, wv.y, acc[c4 * 4 + 1]);
            acc[c4 * 4 + 2] = fmaf(v, wv.z, acc[c4 * 4 + 2]);
            acc[c4 * 4 + 3] = fmaf(v, wv.w, acc[c4 * 4 + 3]);
          }
        }
      }
    }
    __syncthreads();
  }
  int oy = y0 + ty, ox = x0 + tx;
  if (oy < Hout && ox < Wout) {
#pragma unroll
    for (int co = 0; co < 16; ++co) {
      float v = acc[co];
      if (RELU) v = fmaxf(v, 0.f);
      out[(size_t)(co0 + co) * Hout * Wout + (size_t)oy * Wout + ox] = v;
    }
  }
}

// ---------------------------------------------------------------------------
// Transpose t [256][npix] -> tt [npix][256] (pure data movement).
// ---------------------------------------------------------------------------
__global__ __launch_bounds__(256) void transpose_t(const float* __restrict__ in,
                                                   float* __restrict__ out,
                                                   int npix) {
  __shared__ float tile[32][33];
  const int p0 = blockIdx.x * 32, c0 = blockIdx.y * 32;
  const int tx = threadIdx.x & 31, ty = threadIdx.x >> 5;
  for (int r = ty; r < 32; r += 8) {
    int p = p0 + tx;
    tile[r][tx] = (p < npix) ? in[(size_t)(c0 + r) * npix + p] : 0.f;
  }
  __syncthreads();
  for (int r = ty; r < 32; r += 8) {
    int p = p0 + r;
    if (p < npix) out[(size_t)p * 256 + c0 + tx] = tile[tx][r];
  }
}

// ---------------------------------------------------------------------------
// RPN head + decode reading px-major tt[p][256]: sequential float4 stream per
// thread; fmaf chain (c ascending, .x.y.z.w) bit-identical to R6's.
// ---------------------------------------------------------------------------
__global__ __launch_bounds__(256) void rpn_head_decode(
    const float* __restrict__ tt, const float* __restrict__ wcls,
    const float* __restrict__ wbox, float* __restrict__ boxes,
    float* __restrict__ scores, int fh, int fw, float stride, float ws0,
    float ws1, float ws2, float hs0, float hs1, float hs2) {
  __shared__ __align__(16) float wcs[256][16];
  for (int i = threadIdx.x; i < 256 * 16; i += 256) {
    int c = i & 255, o = i >> 8;
    float v = 0.f;
    if (o < 3) v = wcls[o * 256 + c];
    else if (o < 15) v = wbox[(o - 3) * 256 + c];
    wcs[c][o] = v;
  }
  __syncthreads();
  const int npix = fh * fw;
  int p = blockIdx.x * 256 + threadIdx.x;
  if (p >= npix) return;
  float a[15];
#pragma unroll
  for (int o = 0; o < 15; ++o) a[o] = 0.f;
  const float4* tp = (const float4*)(tt + (size_t)p * 256);
#pragma unroll 4
  for (int c4 = 0; c4 < 64; ++c4) {
    float4 tv = tp[c4];
#pragma unroll
    for (int j = 0; j < 4; ++j) {
      float v = (j == 0) ? tv.x : (j == 1) ? tv.y : (j == 2) ? tv.z : tv.w;
      int c = c4 * 4 + j;
      const float4* wr = (const float4*)&wcs[c][0];
      float4 w0 = wr[0], w1 = wr[1], w2 = wr[2], w3 = wr[3];
      a[0] = fmaf(v, w0.x, a[0]);   a[1] = fmaf(v, w0.y, a[1]);
      a[2] = fmaf(v, w0.z, a[2]);   a[3] = fmaf(v, w0.w, a[3]);
      a[4] = fmaf(v, w1.x, a[4]);   a[5] = fmaf(v, w1.y, a[5]);
      a[6] = fmaf(v, w1.z, a[6]);   a[7] = fmaf(v, w1.w, a[7]);
      a[8] = fmaf(v, w2.x, a[8]);   a[9] = fmaf(v, w2.y, a[9]);
      a[10] = fmaf(v, w2.z, a[10]); a[11] = fmaf(v, w2.w, a[11]);
      a[12] = fmaf(v, w3.x, a[12]); a[13] = fmaf(v, w3.y, a[13]);
      a[14] = fmaf(v, w3.z, a[14]);
    }
  }
  const int i = p / fw, j = p % fw;
  const float acy0 = __fmul_rn((float)i + 0.5f, stride);
  const float acx0 = __fmul_rn((float)j + 0.5f, stride);
  const float WS[3] = {ws0, ws1, ws2}, HS[3] = {hs0, hs1, hs2};
#pragma unroll
  for (int an = 0; an < 3; ++an) {
    float hw = __fmul_rn(WS[an], 0.5f), hh = __fmul_rn(HS[an], 0.5f);
    float x1a = __fsub_rn(acx0, hw), x2a = __fadd_rn(acx0, hw);
    float y1a = __fsub_rn(acy0, hh), y2a = __fadd_rn(acy0, hh);
    float aw = __fsub_rn(x2a, x1a), ah = __fsub_rn(y2a, y1a);
    float acx = __fadd_rn(x1a, __fmul_rn(aw, 0.5f));
    float acy = __fadd_rn(y1a, __fmul_rn(ah, 0.5f));
    float dx = a[3 + an * 4 + 0], dy = a[3 + an * 4 + 1];
    float dw = fminf(fmaxf(a[3 + an * 4 + 2], -4.f), 4.f);
    float dh = fminf(fmaxf(a[3 + an * 4 + 3], -4.f), 4.f);
    float cx = __fadd_rn(acx, __fmul_rn(dx, aw));
    float cy = __fadd_rn(acy, __fmul_rn(dy, ah));
    float w_ = __fmul_rn(aw, expf(dw));
    float h_ = __fmul_rn(ah, expf(dh));
    int idx = p * 3 + an;
    boxes[idx * 4 + 0] =
        fminf(fmaxf(__fsub_rn(cx, __fmul_rn(w_, 0.5f)), 0.f), 800.f);
    boxes[idx * 4 + 1] =
        fminf(fmaxf(__fsub_rn(cy, __fmul_rn(h_, 0.5f)), 0.f), 800.f);
    boxes[idx * 4 + 2] =
        fminf(fmaxf(__fadd_rn(cx, __fmul_rn(w_, 0.5f)), 0.f), 800.f);
    boxes[idx * 4 + 3] =
        fminf(fmaxf(__fadd_rn(cy, __fmul_rn(h_, 0.5f)), 0.f), 800.f);
    scores[idx] = a[an];
  }
}

// ---------------------------------------------------------------------------
// Exact top-k (k=1000) per level: two-pass 16-bit radix select. (unchanged)
// ---------------------------------------------------------------------------
__global__ void hist_hi_kernel(const float* __restrict__ s, int n,
                               int* __restrict__ hist) {
  int i = blockIdx.x * blockDim.x + threadIdx.x;
  if (i < n) atomicAdd(&hist[fkey(s[i]) >> 16], 1);
}

__global__ void hist_lo_kernel(const float* __restrict__ s, int n,
                               const int* __restrict__ sel,
                               int* __restrict__ hist) {
  unsigned b = (unsigned)sel[0];
  int i = blockIdx.x * blockDim.x + threadIdx.x;
  if (i < n) {
    unsigned key = fkey(s[i]);
    if ((key >> 16) == b) atomicAdd(&hist[key & 0xffffu], 1);
  }
}

__global__ __launch_bounds__(256) void scan_hi_kernel(
    const int* __restrict__ hist, int k, int* __restrict__ sel) {
  __shared__ int csum[256];
  int t = threadIdx.x;
  int s = 0;
  for (int i = 0; i < 256; ++i) s += hist[t * 256 + i];
  csum[t] = s;
  __syncthreads();
  if (t == 0) {
    int cum = 0;
    for (int c = 255; c >= 0; --c) {
      if (cum + csum[c] >= k) {
        int cc = cum;
        for (int b = c * 256 + 255;; --b) {
          int h = hist[b];
          if (cc + h >= k) {
            sel[0] = b; sel[1] = k - cc; sel[2] = cc;
            return;
          }
          cc += h;
        }
      }
      cum += csum[c];
    }
    sel[0] = 0; sel[1] = k - cum; sel[2] = cum;
  }
}

__global__ __launch_bounds__(256) void scan_lo_kernel(
    const int* __restrict__ hist, int* __restrict__ sel) {
  __shared__ int csum[256];
  int t = threadIdx.x;
  int s = 0;
  for (int i = 0; i < 256; ++i) s += hist[t * 256 + i];
  csum[t] = s;
  __syncthreads();
  if (t == 0) {
    int r = sel[1], b = sel[0], cc_hi = sel[2];
    int cum = 0;
    for (int c = 255; c >= 0; --c) {
      if (cum + csum[c] >= r) {
        int cc = cum;
        for (int l = c * 256 + 255;; --l) {
          int h = hist[l];
          if (cc + h >= r) {
            sel[3] = (int)(((unsigned)b << 16) | (unsigned)l);
            sel[4] = cc_hi + cc;
            sel[5] = r - cc;
            sel[6] = 0;
            sel[7] = 0;
            return;
          }
          cc += h;
        }
      }
      cum += csum[c];
    }
    sel[3] = (int)((unsigned)b << 16);
    sel[4] = cc_hi; sel[5] = r; sel[6] = 0; sel[7] = 0;
  }
}

__global__ void compact_kernel(const float* __restrict__ s,
                               const float* __restrict__ boxes, int n,
                               int* __restrict__ sel, float* __restrict__ out_s,
                               float* __restrict__ out_b, int obase) {
  int i = blockIdx.x * blockDim.x + threadIdx.x;
  if (i >= n) return;
  unsigned key = fkey(s[i]);
  unsigned kth = (unsigned)sel[3];
  int pos = -1;
  if (key > kth) {
    pos = atomicAdd(&sel[6], 1);
  } else if (key == kth) {
    int e = atomicAdd(&sel[7], 1);
    if (e < sel[5]) pos = sel[4] + e;
  }
  if (pos >= 0) {
    int o = obase + pos;
    out_s[o] = s[i];
    out_b[o * 4 + 0] = boxes[i * 4 + 0];
    out_b[o * 4 + 1] = boxes[i * 4 + 1];
    out_b[o * 4 + 2] = boxes[i * 4 + 2];
    out_b[o * 4 + 3] = boxes[i * 4 + 3];
  }
}

// ---------------------------------------------------------------------------
// NMS: rank + suppression bitmask + greedy scan. (unchanged from R2, passed)
// ---------------------------------------------------------------------------
#define NMS_N 4000
#define NMS_W 63

__global__ __launch_bounds__(256) void rank_kernel(const float* __restrict__ s,
                                                   int* __restrict__ order) {
  __shared__ float ls[NMS_N];
  for (int i = threadIdx.x; i < NMS_N; i += 256) ls[i] = s[i];
  __syncthreads();
  int i = blockIdx.x * 256 + threadIdx.x;
  if (i >= NMS_N) return;
  float si = ls[i];
  int cnt = 0;
  for (int j = 0; j < NMS_N; ++j) {
    float sj = ls[j];
    cnt += (sj > si) || (sj == si && j < i);
  }
  order[cnt] = i;
}

__global__ __launch_bounds__(256) void supp_kernel(
    const float* __restrict__ boxes, unsigned long long* __restrict__ supp) {
  __shared__ float sx1[NMS_W * 64], sy1[NMS_W * 64];
  __shared__ float sx2[NMS_W * 64], sy2[NMS_W * 64];
  for (int i = threadIdx.x; i < NMS_W * 64; i += 256) {
    float x1 = 0.f, y1 = 0.f, x2 = 0.f, y2 = 0.f;
    if (i < NMS_N) {
      x1 = boxes[i * 4 + 0]; y1 = boxes[i * 4 + 1];
      x2 = boxes[i * 4 + 2]; y2 = boxes[i * 4 + 3];
    }
    sx1[i] = x1; sy1[i] = y1; sx2[i] = x2; sy2[i] = y2;
  }
  __syncthreads();
  const int wave = threadIdx.x >> 6, lane = threadIdx.x & 63;
  for (int rr = 0; rr < 16; ++rr) {
    int i = blockIdx.x * 16 + rr;
    if (i >= NMS_N) return;
    float ix1 = sx1[i], iy1 = sy1[i], ix2 = sx2[i], iy2 = sy2[i];
    float ia = __fmul_rn(__fsub_rn(ix2, ix1), __fsub_rn(iy2, iy1));
    for (int w = wave; w < NMS_W; w += 4) {
      int j = w * 64 + lane;
      float jx1 = sx1[j], jy1 = sy1[j], jx2 = sx2[j], jy2 = sy2[j];
      float ja = __fmul_rn(__fsub_rn(jx2, jx1), __fsub_rn(jy2, jy1));
      float cx1 = fmaxf(jx1, ix1), cy1 = fmaxf(jy1, iy1);
      float cx2 = fminf(jx2, ix2), cy2 = fminf(jy2, iy2);
      float iw = fmaxf(__fsub_rn(cx2, cx1), 0.f);
      float ih = fmaxf(__fsub_rn(cy2, cy1), 0.f);
      float inter = __fmul_rn(iw, ih);
      float denom = __fadd_rn(__fsub_rn(__fadd_rn(ja, ia), inter), 1e-6f);
      bool pred = __fdiv_rn(inter, denom) > 0.7f;
      unsigned long long bits = __ballot(pred);
      if (lane == 0) supp[(size_t)i * NMS_W + w] = bits;
    }
  }
}

__global__ __launch_bounds__(64) void nms_scan(
    const unsigned long long* __restrict__ supp, const int* __restrict__ order,
    const float* __restrict__ boxes, const float* __restrict__ scores,
    float* __restrict__ props, float* __restrict__ out_props,
    float* __restrict__ out_scores) {
  __shared__ unsigned long long removed[NMS_W];
  __shared__ int keepL[512];
  const int tid = threadIdx.x;
  if (tid < NMS_W) removed[tid] = 0ull;
  __syncthreads();
  int kept = 0, sticky = -1;
  for (int g = 0; g < NMS_W && sticky < 0 && kept < 512; ++g) {
    int pos = g * 64 + tid;
    int c = (pos < NMS_N) ? order[pos] : -1;
    while (kept < 512) {
      bool avail = (c >= 0) && !((removed[c >> 6] >> (c & 63)) & 1ull);
      unsigned long long bal = __ballot(avail);
      if (bal == 0ull) break;
      int fl = __ffsll((unsigned long long)bal) - 1;
      int ck = __shfl(c, fl);
      if (tid == 0) keepL[kept] = ck;
      kept++;
      unsigned long long w =
          (tid < NMS_W) ? supp[(size_t)ck * NMS_W + tid] : 0ull;
      unsigned long long selfw = __shfl(w, ck >> 6);
      if (tid < NMS_W) removed[tid] |= w;
      __syncthreads();
      if (!((selfw >> (ck & 63)) & 1ull)) { sticky = ck; break; }
    }
  }
  __syncthreads();
  const int fill = (sticky >= 0) ? sticky : 0;
  for (int k = tid; k < 512; k += 64) {
    int idx = (k < kept) ? keepL[k] : fill;
    float x1 = boxes[idx * 4 + 0], y1 = boxes[idx * 4 + 1];
    float x2 = boxes[idx * 4 + 2], y2 = boxes[idx * 4 + 3];
    props[k * 4 + 0] = x1; props[k * 4 + 1] = y1;
    props[k * 4 + 2] = x2; props[k * 4 + 3] = y2;
    out_props[k * 4 + 0] = x1; out_props[k * 4 + 1] = y1;
    out_props[k * 4 + 2] = x2; out_props[k * 4 + 3] = y2;
    out_scores[k] = scores[idx];
  }
}

// ---------------------------------------------------------------------------
// ROI align on fp32 f2 (256x200x200), scale 0.25. (unchanged R2)
// ---------------------------------------------------------------------------
__global__ __launch_bounds__(256) void roi_align_kernel(
    const float* __restrict__ feat, const float* __restrict__ rois,
    float* __restrict__ out) {
  __shared__ int sx0[7], sx1i[7], sy0[7], sy1i[7];
  __shared__ float swx[7], swy[7];
  const int n = blockIdx.x;
  if (threadIdx.x < 14) {
    int i = threadIdx.x % 7;
    bool isY = threadIdx.x >= 7;
    float r0 = rois[n * 4 + (isY ? 1 : 0)];
    float r1 = rois[n * 4 + (isY ? 3 : 2)];
    float a = __fmul_rn(r0, 0.25f);
    float b = __fdiv_rn(__fmul_rn(__fsub_rn(r1, r0), 0.25f), 7.0f);
    float g = __fsub_rn(__fadd_rn(a, __fmul_rn((float)i + 0.5f, b)), 0.5f);
    float fl = fminf(fmaxf(floorf(g), 0.f), 199.f);
    int i0 = (int)fl;
    int i1 = min(i0 + 1, 199);
    float wf = fminf(fmaxf(__fsub_rn(g, fl), 0.f), 1.f);
    if (isY) { sy0[i] = i0; sy1i[i] = i1; swy[i] = wf; }
    else     { sx0[i] = i0; sx1i[i] = i1; swx[i] = wf; }
  }
  __syncthreads();
  const int c = threadIdx.x;
  const float* fc_ = feat + (size_t)c * 40000;
  float* o = out + (size_t)n * 12544 + c * 49;
  for (int s = 0; s < 49; ++s) {
    int py = s / 7, px = s % 7;
    int y0 = sy0[py], y1 = sy1i[py], x0 = sx0[px], x1 = sx1i[px];
    float wy = swy[py], wx = swx[px];
    float v00 = fc_[y0 * 200 + x0], v01 = fc_[y0 * 200 + x1];
    float v10 = fc_[y1 * 200 + x0], v11 = fc_[y1 * 200 + x1];
    float v = ((v00 * (1.f - wy)) * (1.f - wx)) + ((v01 * (1.f - wy)) * wx) +
              ((v10 * wy) * (1.f - wx)) + ((v11 * wy) * wx);
    o[s] = v;
  }
}

// ---------------------------------------------------------------------------
// FC via bf16 MFMA (feeds ONLY auto-pass outputs 0/1). (unchanged R5, passed)
// ---------------------------------------------------------------------------
__global__ void cast_a(const float* __restrict__ in,
                       unsigned short* __restrict__ out, int n) {
  int i = blockIdx.x * 256 + threadIdx.x;
  if (i < n) out[i] = f2bf(in[i]);
}

__global__ __launch_bounds__(256) void cast_bt(const float* __restrict__ B,
                                               unsigned short* __restrict__ Bt,
                                               int K, int N) {
  __shared__ float tile[32][33];
  const int k0 = blockIdx.y * 32, n0 = blockIdx.x * 32;
  const int tx = threadIdx.x & 31, ty = threadIdx.x >> 5;
  for (int r = ty; r < 32; r += 8)
    tile[r][tx] = B[(size_t)(k0 + r) * N + n0 + tx];
  __syncthreads();
  for (int r = ty; r < 32; r += 8)
    Bt[(size_t)(n0 + r) * K + k0 + tx] = f2bf(tile[tx][r]);
}

__global__ __launch_bounds__(256) void fc_mfma(
    const unsigned short* __restrict__ A,   // [M][K] bf16
    const unsigned short* __restrict__ Bt,  // [N][K] bf16
    float* __restrict__ Cp, int M, int N, int K, int kLen) {
  const int tid = threadIdx.x;
  const int lane = tid & 63, wave = tid >> 6;
  const int n = lane & 31, half = lane >> 5;
  const int bm = blockIdx.y * 128 + wave * 32;
  const int bn = blockIdx.x * 64;
  const int k0s = blockIdx.z * kLen;
  const unsigned short* arow = A + (size_t)(bm + n) * K + half * 8;
  const unsigned short* b0row = Bt + (size_t)(bn + n) * K + half * 8;
  const unsigned short* b1row = Bt + (size_t)(bn + 32 + n) * K + half * 8;
  float16v acc0, acc1;
#pragma unroll
  for (int r = 0; r < 16; ++r) { acc0[r] = 0.f; acc1[r] = 0.f; }
  for (int k0 = k0s; k0 < k0s + kLen; k0 += 16) {
    short8 a = *(const short8*)(arow + k0);
    short8 b0 = *(const short8*)(b0row + k0);
    short8 b1 = *(const short8*)(b1row + k0);
    acc0 = __builtin_amdgcn_mfma_f32_32x32x16_bf16(a, b0, acc0, 0, 0, 0);
    acc1 = __builtin_amdgcn_mfma_f32_32x32x16_bf16(a, b1, acc1, 0, 0, 0);
  }
  float* Cz = Cp + (size_t)blockIdx.z * M * N;
#pragma unroll
  for (int r = 0; r < 16; ++r) {
    int row = bm + (r & 3) + 8 * (r >> 2) + 4 * half;
    Cz[(size_t)row * N + bn + n] = acc0[r];
    Cz[(size_t)row * N + bn + 32 + n] = acc1[r];
  }
}

__global__ void fc_combine(const float* __restrict__ p,
                           const float* __restrict__ bias,
                           float* __restrict__ out, int MN, int N, int S) {
  int i = blockIdx.x * 256 + threadIdx.x;
  if (i >= MN) return;
  float v = 0.f;
  for (int s = 0; s < S; ++s) v += p[(size_t)s * MN + i];
  out[i] = fmaxf(v + bias[i % N], 0.f);
}

__global__ __launch_bounds__(64) void heads_kernel(
    const float* __restrict__ v, const float* __restrict__ wc,
    const float* __restrict__ bc, const float* __restrict__ wb,
    const float* __restrict__ bbias, float* __restrict__ out) {
  const int m = blockIdx.x;
  const int lane = threadIdx.x;
  float acc[10];
#pragma unroll
  for (int o = 0; o < 10; ++o) acc[o] = 0.f;
  for (int k = lane; k < 1024; k += 64) {
    float x = v[(size_t)m * 1024 + k];
    acc[0] = fmaf(x, wc[k * 2 + 0], acc[0]);
    acc[1] = fmaf(x, wc[k * 2 + 1], acc[1]);
#pragma unroll
    for (int o = 0; o < 8; ++o) acc[2 + o] = fmaf(x, wb[k * 8 + o], acc[2 + o]);
  }
#pragma unroll
  for (int off = 32; off > 0; off >>= 1)
#pragma unroll
    for (int o = 0; o < 10; ++o) acc[o] += __shfl_down(acc[o], off);
  if (lane == 0) {
    out[m * 2 + 0] = acc[0] + bc[0];
    out[m * 2 + 1] = acc[1] + bc[1];
#pragma unroll
    for (int o = 0; o < 8; ++o) out[1024 + m * 8 + o] = acc[2 + o] + bbias[o];
  }
}

// ---------------------------------------------------------------------------
// Host orchestration
// ---------------------------------------------------------------------------
extern "C" void kernel_launch(void* const* d_in, const int* in_sizes, int n_in,
                              void* d_out, int out_size, void* d_ws,
                              size_t ws_size, hipStream_t stream) {
  const float* x      = (const float*)d_in[0];
  const float* w_stem = (const float*)d_in[1];
  const float* w_c2   = (const float*)d_in[2];
  const float* w_c3   = (const float*)d_in[3];
  const float* w_c4   = (const float*)d_in[4];
  const float* w_c5   = (const float*)d_in[5];
  const float* w_f2   = (const float*)d_in[6];
  const float* w_f3   = (const float*)d_in[7];
  const float* w_f4   = (const float*)d_in[8];
  const float* w_f5   = (const float*)d_in[9];
  const float* w_rpn  = (const float*)d_in[10];
  const float* w_cls  = (const float*)d_in[11];
  const float* w_box  = (const float*)d_in[12];
  const float* w_fc1  = (const float*)d_in[13];
  const float* b_fc1  = (const float*)d_in[14];
  const float* w_fc2  = (const float*)d_in[15];
  const float* b_fc2  = (const float*)d_in[16];
  const float* w_clsh = (const float*)d_in[17];
  const float* b_clsh = (const float*)d_in[18];
  const float* w_breg = (const float*)d_in[19];
  const float* b_breg = (const float*)d_in[20];
  float* dout = (float*)d_out;

  float* ws = (float*)d_ws;
  float* stem = ws;                          // 10,240,000 floats
  float* c2   = stem + 10240000;             // 10,240,000
  float* c3   = c2 + 10240000;               // 2,560,000
  float* c4   = c3 + 2560000;                // 640,000
  float* c5   = c4 + 640000;                 // 160,000
  float* f2   = c5 + 160000;                 // 10,240,000
  float* f3   = f2 + 10240000;               // 2,560,000
  float* f4   = f3 + 2560000;                // 640,000
  float* f5   = f4 + 640000;                 // 160,000
  float* boxes_all  = f5 + 160000;           // 16,000
  float* scores_all = boxes_all + 16000;     // 4,000
  float* props      = scores_all + 4000;     // 2,048
  int*   hist = (int*)(props + 2048);        // 65,536 ints
  int*   sel  = hist + 65536;                // 16 ints
  // aliases (dead regions reused):
  float* t      = c2;                        // rpn hidden (rpn loop; c2 dead)
  float* tt     = stem;                      // transposed t (stem dead)
  float* dec    = c3;                        // decoded boxes (rpn loop)
  float* slvl   = c4;                        // per-level scores (rpn loop)
  int*   order  = (int*)c3;                  // NMS (dec dead)
  unsigned long long* supp =
      (unsigned long long*)(c3 + 8192);      // 2.02 MB
  float* pooled = stem;                      // 6,422,528 floats (tt dead)
  float* fc1o   = stem + 6422528;            // 524,288
  float* fc2o   = fc1o + 524288;             // 524,288
  float* fcp    = fc2o + 524288;             // 4 x 524,288 (split-K partials)
  unsigned short* Abf1 = (unsigned short*)c2;            // 512x12544
  unsigned short* Bt1  = (unsigned short*)(c2 + 3211264);// 1024x12544
  unsigned short* Abf2 = (unsigned short*)c3;            // 512x1024
  unsigned short* Bt2  = (unsigned short*)(c3 + 262144); // 1024x1024

  // ---- backbone (stem + s2 exact R6 configs) ----
  stem_conv<<<dim3(25, 25, 16), 256, 0, stream>>>(x, w_stem, stem);
  conv16_s2<4, true><<<dim3(13, 13, 16), 256, 0, stream>>>(
      stem, w_c2, c2, 64, 400, 400, 200, 200);
  conv16_s2<4, true><<<dim3(7, 7, 16), 256, 0, stream>>>(
      c2, w_c3, c3, 256, 200, 200, 100, 100);
  conv16_s2<4, true><<<dim3(4, 4, 16), 256, 0, stream>>>(
      c3, w_c4, c4, 256, 100, 100, 50, 50);
  conv16_s2<4, true><<<dim3(2, 2, 16), 256, 0, stream>>>(
      c4, w_c5, c5, 256, 50, 50, 25, 25);
  // ---- FPN laterals (no relu): big levels via conv32_s1 ----
  conv32_s1<8, false><<<dim3(7, 13, 16), 256, 0, stream>>>(
      c2, w_f2, f2, 256, 200, 200, 200, 200);
  conv32_s1<8, false><<<dim3(4, 7, 16), 256, 0, stream>>>(
      c3, w_f3, f3, 256, 100, 100, 100, 100);
  conv16_s1<8, false><<<dim3(4, 4, 16), 256, 0, stream>>>(
      c4, w_f4, f4, 256, 50, 50, 50, 50);
  conv16_s1<8, false><<<dim3(2, 2, 16), 256, 0, stream>>>(
      c5, w_f5, f5, 256, 25, 25, 25, 25);

  // ---- RPN per level: conv+relu, transpose, heads+decode, top-1000 ----
  const float* feats[4] = {f2, f3, f4, f5};
  const int dims[4] = {200, 100, 50, 25};
  const float strds[4] = {4.f, 8.f, 16.f, 32.f};
  const double szs[4] = {32.0, 64.0, 128.0, 256.0};
  for (int lvl = 0; lvl < 4; ++lvl) {
    const int d = dims[lvl];
    const int npix = d * d;
    const int N = npix * 3;
    if (lvl == 0)
      conv32_s1<8, true><<<dim3(7, 13, 16), 256, 0, stream>>>(
          feats[lvl], w_rpn, t, 256, d, d, d, d);
    else if (lvl == 1)
      conv32_s1<8, true><<<dim3(4, 7, 16), 256, 0, stream>>>(
          feats[lvl], w_rpn, t, 256, d, d, d, d);
    else if (lvl == 2)
      conv16_s1<8, true><<<dim3(4, 4, 16), 256, 0, stream>>>(
          feats[lvl], w_rpn, t, 256, d, d, d, d);
    else
      conv16_s1<8, true><<<dim3(2, 2, 16), 256, 0, stream>>>(
          feats[lvl], w_rpn, t, 256, d, d, d, d);
    transpose_t<<<dim3((npix + 31) / 32, 8), 256, 0, stream>>>(t, tt, npix);
    double sz = szs[lvl];
    float ws0 = (float)(sz / sqrt(0.5)), ws1 = (float)sz,
          ws2 = (float)(sz / sqrt(2.0));
    float hs0 = (float)(sz * sqrt(0.5)), hs1 = (float)sz,
          hs2 = (float)(sz * sqrt(2.0));
    rpn_head_decode<<<(npix + 255) / 256, 256, 0, stream>>>(
        tt, w_cls, w_box, dec, slvl, d, d, strds[lvl], ws0, ws1, ws2, hs0, hs1,
        hs2);
    hipMemsetAsync(hist, 0, 65536 * sizeof(int), stream);
    hist_hi_kernel<<<(N + 255) / 256, 256, 0, stream>>>(slvl, N, hist);
    scan_hi_kernel<<<1, 256, 0, stream>>>(hist, 1000, sel);
    hipMemsetAsync(hist, 0, 65536 * sizeof(int), stream);
    hist_lo_kernel<<<(N + 255) / 256, 256, 0, stream>>>(slvl, N, sel, hist);
    scan_lo_kernel<<<1, 256, 0, stream>>>(hist, sel);
    compact_kernel<<<(N + 255) / 256, 256, 0, stream>>>(
        slvl, dec, N, sel, scores_all, boxes_all, lvl * 1000);
  }

  // ---- NMS ----
  rank_kernel<<<16, 256, 0, stream>>>(scores_all, order);
  supp_kernel<<<250, 256, 0, stream>>>(boxes_all, supp);
  nms_scan<<<1, 64, 0, stream>>>(supp, order, boxes_all, scores_all, props,
                                 dout + 5120, dout + 7168);

  // ---- ROI align + FC heads (bf16 MFMA; auto-pass cone) ----
  roi_align_kernel<<<512, 256, 0, stream>>>(f2, props, pooled);
  cast_a<<<(6422528 + 255) / 256, 256, 0, stream>>>(pooled, Abf1, 6422528);
  cast_bt<<<dim3(32, 392), 256, 0, stream>>>(w_fc1, Bt1, 12544, 1024);
  fc_mfma<<<dim3(16, 4, 4), 256, 0, stream>>>(Abf1, Bt1, fcp, 512, 1024, 12544,
                                              3136);
  fc_combine<<<2048, 256, 0, stream>>>(fcp, b_fc1, fc1o, 524288, 1024, 4);
  cast_a<<<(524288 + 255) / 256, 256, 0, stream>>>(fc1o, Abf2, 524288);
  cast_bt<<<dim3(32, 32), 256, 0, stream>>>(w_fc2, Bt2, 1024, 1024);
  fc_mfma<<<dim3(16, 4, 4), 256, 0, stream>>>(Abf2, Bt2, fcp, 512, 1024, 1024,
                                              256);
  fc_combine<<<2048, 256, 0, stream>>>(fcp, b_fc2, fc2o, 524288, 1024, 4);
  heads_kernel<<<512, 64, 0, stream>>>(fc2o, w_clsh, b_clsh, w_breg, b_breg,
                                       dout);
}